// Round 1
// baseline (298.532 us; speedup 1.0000x reference)
//
#include <hip/hip_runtime.h>

// Shapes fixed by the reference: B=64, N=576, C=1024.
#define B_ 64
#define N_ 576
#define C_ 1024

// K1: logits[b*N+n] = dot(V[b,n,:], W[0:C]); one 64-lane wave per row.
__global__ __launch_bounds__(256) void k_logits(const float* __restrict__ V,
                                                const float* __restrict__ W,
                                                float* __restrict__ logits,
                                                int BN) {
    int wave = (int)((blockIdx.x * blockDim.x + threadIdx.x) >> 6);
    int lane = threadIdx.x & 63;
    if (wave >= BN) return;
    const float4* v4 = (const float4*)(V + (size_t)wave * C_);
    const float4* w4 = (const float4*)W;  // only first C floats used
    float acc = 0.f;
#pragma unroll
    for (int it = 0; it < C_ / (64 * 4); ++it) {
        float4 v = v4[lane + it * 64];
        float4 w = w4[lane + it * 64];
        acc += v.x * w.x + v.y * w.y + v.z * w.z + v.w * w.w;
    }
#pragma unroll
    for (int off = 32; off; off >>= 1) acc += __shfl_xor(acc, off, 64);
    if (lane == 0) logits[wave] = acc;
}

// K2: per-batch top-K mask via O(N^2) rank; ties broken to lower index
// (matches jnp.argmax first-occurrence in the iterative scan).
__global__ __launch_bounds__(N_) void k_mask(const float* __restrict__ logits,
                                             const float* __restrict__ token_budget,
                                             float* __restrict__ mask_out,   // d_out tail
                                             float* __restrict__ mask_ws) {  // ws copy for K3
    __shared__ float sl[N_];
    int b = blockIdx.x;
    int t = threadIdx.x;
    sl[t] = logits[b * N_ + t];
    __syncthreads();
    // K = clip((int)(budget*N), 1, N) -- astype(int32) truncates like (int) cast
    int K = (int)(token_budget[b] * (float)N_);
    K = K < 1 ? 1 : (K > N_ ? N_ : K);
    float ln = sl[t];
    int rank = 0;
    for (int m = 0; m < N_; ++m) {
        float lm = sl[m];
        rank += (lm > ln) || (lm == ln && m < t);
    }
    float mv = (rank < K) ? 1.0f : 0.0f;
    mask_out[b * N_ + t] = mv;
    mask_ws[b * N_ + t] = mv;
}

// K3: out[b,n,c] = V[b,n,c] * mask[b,n], float4-vectorized.
__global__ __launch_bounds__(256) void k_scale(const float* __restrict__ V,
                                               const float* __restrict__ mask,
                                               float* __restrict__ out,
                                               int total4) {
    int i = (int)(blockIdx.x * blockDim.x + threadIdx.x);
    if (i >= total4) return;
    float m = mask[i >> 8];  // C/4 = 256 float4 per row
    float4 v = ((const float4*)V)[i];
    v.x *= m; v.y *= m; v.z *= m; v.w *= m;
    ((float4*)out)[i] = v;
}

extern "C" void kernel_launch(void* const* d_in, const int* in_sizes, int n_in,
                              void* d_out, int out_size, void* d_ws, size_t ws_size,
                              hipStream_t stream) {
    const float* V  = (const float*)d_in[0];  // [B,N,C]
    const float* tb = (const float*)d_in[1];  // [B]
    // d_in[2] (budget_embedding), d_in[3][C..2C), d_in[4] (bias) are rank-preserving
    // per-row constants -> do not affect mask or outputs; only W[0:C] is needed.
    const float* W  = (const float*)d_in[3];  // [1,2C]

    float* out_feat = (float*)d_out;                         // [B,N,C]
    float* out_mask = (float*)d_out + (size_t)B_ * N_ * C_;  // [B,N]

    float* ws_logits = (float*)d_ws;              // B*N floats
    float* ws_mask   = (float*)d_ws + B_ * N_;    // B*N floats

    const int BN = B_ * N_;
    // K1: one wave per row, 4 waves per 256-thread block
    k_logits<<<(BN + 3) / 4, 256, 0, stream>>>(V, W, ws_logits, BN);
    // K2: one block per batch element
    k_mask<<<B_, N_, 0, stream>>>(ws_logits, tb, out_mask, ws_mask);
    // K3: one thread per float4
    const int total4 = B_ * N_ * C_ / 4;
    k_scale<<<(total4 + 255) / 256, 256, 0, stream>>>(V, ws_mask, out_feat, total4);
}

// Round 3
// 282.972 us; speedup vs baseline: 1.0550x; 1.0550x over previous
//
#include <hip/hip_runtime.h>

// Shapes fixed by the reference: B=64, N=576, C=1024.
#define B_ 64
#define N_ 576
#define C_ 1024
#define ROWS_PER_BLK 4

typedef float v4f __attribute__((ext_vector_type(4)));  // native vector: OK for nontemporal builtins

// K1: logits[b*N+n] = dot(V[b,n,:], W[0:C]); one 64-lane wave per row.
// Budget-embedding term + bias are constant per b and rank-preserving -> dropped.
__global__ __launch_bounds__(256) void k_logits(const float* __restrict__ V,
                                                const float* __restrict__ W,
                                                float* __restrict__ logits,
                                                int BN) {
    int wave = (int)((blockIdx.x * blockDim.x + threadIdx.x) >> 6);
    int lane = threadIdx.x & 63;
    if (wave >= BN) return;
    const v4f* v4 = (const v4f*)(V + (size_t)wave * C_);
    const v4f* w4 = (const v4f*)W;  // only first C floats matter for ranking
    float acc = 0.f;
#pragma unroll
    for (int it = 0; it < C_ / (64 * 4); ++it) {  // 4 iters
        v4f v = v4[lane + it * 64];
        v4f w = w4[lane + it * 64];
        acc += v.x * w.x + v.y * w.y + v.z * w.z + v.w * w.w;
    }
#pragma unroll
    for (int off = 32; off; off >>= 1) acc += __shfl_xor(acc, off, 64);
    if (lane == 0) logits[wave] = acc;
}

// K2: per-batch top-K mask via O(N^2) rank; ties broken to lower index
// (matches jnp.argmax first-occurrence semantics of the iterative scan).
__global__ __launch_bounds__(N_) void k_mask(const float* __restrict__ logits,
                                             const float* __restrict__ token_budget,
                                             float* __restrict__ mask_out,   // d_out tail
                                             float* __restrict__ mask_ws) {  // ws copy for K3
    __shared__ float sl[N_];
    int b = blockIdx.x;
    int t = threadIdx.x;
    sl[t] = logits[b * N_ + t];
    __syncthreads();
    // K = clip((int)(budget*N), 1, N) -- astype(int32) truncates toward zero
    int K = (int)(token_budget[b] * (float)N_);
    K = K < 1 ? 1 : (K > N_ ? N_ : K);
    float ln = sl[t];
    int rank = 0;
#pragma unroll 8
    for (int m = 0; m < N_; ++m) {
        float lm = sl[m];
        rank += (lm > ln) || (lm == ln && m < t);
    }
    float mv = (rank < K) ? 1.0f : 0.0f;
    mask_out[b * N_ + t] = mv;
    mask_ws[b * N_ + t] = mv;
}

// K3: out[b,n,:] = mask[b,n] ? V[b,n,:] : 0.  One block covers ROWS_PER_BLK rows;
// branch is block-uniform; kept rows are a pure copy (mask==1.0 exactly);
// dropped rows write zeros WITHOUT reading V (saves ~half the read traffic).
// Nontemporal stores keep the write stream from evicting V from LLC.
__global__ __launch_bounds__(256) void k_scale(const float* __restrict__ V,
                                               const float* __restrict__ mask,
                                               float* __restrict__ out) {
    int row0 = blockIdx.x * ROWS_PER_BLK;
    int t = threadIdx.x;  // 0..255 ; C_/4 == 256 float4 per row
    const v4f z = {0.f, 0.f, 0.f, 0.f};
#pragma unroll
    for (int r = 0; r < ROWS_PER_BLK; ++r) {
        int row = row0 + r;
        float m = mask[row];  // block-uniform
        const v4f* v4 = (const v4f*)(V + (size_t)row * C_);
        v4f* o4 = (v4f*)(out + (size_t)row * C_);
        if (m != 0.0f) {
            v4f v = v4[t];
            __builtin_nontemporal_store(v, &o4[t]);
        } else {
            __builtin_nontemporal_store(z, &o4[t]);
        }
    }
}

extern "C" void kernel_launch(void* const* d_in, const int* in_sizes, int n_in,
                              void* d_out, int out_size, void* d_ws, size_t ws_size,
                              hipStream_t stream) {
    const float* V  = (const float*)d_in[0];  // [B,N,C]
    const float* tb = (const float*)d_in[1];  // [B]
    // d_in[2] (budget_embedding), W[C:2C), bias: per-row rank-preserving constants.
    const float* W  = (const float*)d_in[3];  // [1,2C]

    float* out_feat = (float*)d_out;                         // [B,N,C]
    float* out_mask = (float*)d_out + (size_t)B_ * N_ * C_;  // [B,N]

    float* ws_logits = (float*)d_ws;              // B*N floats
    float* ws_mask   = (float*)d_ws + B_ * N_;    // B*N floats

    const int BN = B_ * N_;
    k_logits<<<(BN + 3) / 4, 256, 0, stream>>>(V, W, ws_logits, BN);
    k_mask<<<B_, N_, 0, stream>>>(ws_logits, tb, out_mask, ws_mask);
    k_scale<<<BN / ROWS_PER_BLK, 256, 0, stream>>>(V, ws_mask, out_feat);
}

// Round 4
// 262.023 us; speedup vs baseline: 1.1393x; 1.0800x over previous
//
#include <hip/hip_runtime.h>

// Shapes fixed by the reference: B=64, N=576, C=1024.
#define B_ 64
#define N_ 576
#define C_ 1024
#define ROWS_PER_BLK 4   // 576 % 4 == 0 -> a block never straddles batches

typedef float v4f __attribute__((ext_vector_type(4)));  // native vector for nontemporal builtins

// K1: logits[b*N+n] = dot(V[b,n,:], W[0:C]); one 64-lane wave per row.
// Budget-embedding term + bias are constant per b and rank-preserving -> dropped.
__global__ __launch_bounds__(256) void k_logits(const float* __restrict__ V,
                                                const float* __restrict__ W,
                                                float* __restrict__ logits,
                                                int BN) {
    int wave = (int)((blockIdx.x * blockDim.x + threadIdx.x) >> 6);
    int lane = threadIdx.x & 63;
    if (wave >= BN) return;
    const v4f* v4 = (const v4f*)(V + (size_t)wave * C_);
    const v4f* w4 = (const v4f*)W;  // only first C floats matter for ranking
    float acc = 0.f;
#pragma unroll
    for (int it = 0; it < C_ / (64 * 4); ++it) {  // 4 iters, full row coalesced
        v4f v = v4[lane + it * 64];
        v4f w = w4[lane + it * 64];
        acc += v.x * w.x + v.y * w.y + v.z * w.z + v.w * w.w;
    }
#pragma unroll
    for (int off = 32; off; off >>= 1) acc += __shfl_xor(acc, off, 64);
    if (lane == 0) logits[wave] = acc;
}

// K23: fused mask + scale. Each block owns 4 rows of one batch b.
//  1) stage batch b's 576 logits from L2-resident ws into LDS
//  2) wave w computes rank of row n0+w (O(N) compares, tie -> lower index,
//     matching jnp.argmax first-occurrence of the iterative gumbel scan);
//     K = clip((int)(budget*N), 1, N)
//  3) mask -> d_out tail + LDS; then copy/zero the 4 rows (block-uniform branch,
//     dropped rows skip the V read entirely; nontemporal stores keep the write
//     stream from evicting LLC-resident V).
__global__ __launch_bounds__(256) void k_mask_scale(const float* __restrict__ V,
                                                    const float* __restrict__ logits,
                                                    const float* __restrict__ token_budget,
                                                    float* __restrict__ out_feat,
                                                    float* __restrict__ out_mask) {
    __shared__ float sl[N_];
    __shared__ float smask[ROWS_PER_BLK];
    int row0 = blockIdx.x * ROWS_PER_BLK;
    int b = row0 / N_;
    int n0 = row0 - b * N_;
    int t = threadIdx.x;

    // stage 576 logits (2*256 + 64)
    sl[t] = logits[b * N_ + t];
    sl[t + 256] = logits[b * N_ + t + 256];
    if (t < 64) sl[t + 512] = logits[b * N_ + t + 512];
    __syncthreads();

    int K = (int)(token_budget[b] * (float)N_);  // astype(int32) truncates toward zero
    K = K < 1 ? 1 : (K > N_ ? N_ : K);

    int w = t >> 6, l = t & 63;
    {
        int n = n0 + w;              // this wave's row (local index in batch)
        float ln = sl[n];
        int rank = 0;
#pragma unroll
        for (int i = 0; i < N_ / 64; ++i) {  // 9 iters
            int m = l + 64 * i;
            float lm = sl[m];
            rank += (lm > ln) || (lm == ln && m < n);
        }
#pragma unroll
        for (int off = 32; off; off >>= 1) rank += __shfl_xor(rank, off, 64);
        if (l == 0) {
            float mv = (rank < K) ? 1.0f : 0.0f;
            smask[w] = mv;
            out_mask[b * N_ + n] = mv;
        }
    }
    __syncthreads();

    const v4f z = {0.f, 0.f, 0.f, 0.f};
#pragma unroll
    for (int r = 0; r < ROWS_PER_BLK; ++r) {
        int row = row0 + r;
        float m = smask[r];          // block-uniform
        const v4f* v4 = (const v4f*)(V + (size_t)row * C_);
        v4f* o4 = (v4f*)(out_feat + (size_t)row * C_);
        if (m != 0.0f) {
            v4f v = v4[t];           // C/4 == 256 float4 per row
            __builtin_nontemporal_store(v, &o4[t]);
        } else {
            __builtin_nontemporal_store(z, &o4[t]);
        }
    }
}

extern "C" void kernel_launch(void* const* d_in, const int* in_sizes, int n_in,
                              void* d_out, int out_size, void* d_ws, size_t ws_size,
                              hipStream_t stream) {
    const float* V  = (const float*)d_in[0];  // [B,N,C]
    const float* tb = (const float*)d_in[1];  // [B]
    // d_in[2] (budget_embedding), W[C:2C), bias: per-row rank-preserving constants.
    const float* W  = (const float*)d_in[3];  // [1,2C]

    float* out_feat = (float*)d_out;                         // [B,N,C]
    float* out_mask = (float*)d_out + (size_t)B_ * N_ * C_;  // [B,N]

    float* ws_logits = (float*)d_ws;  // B*N floats

    const int BN = B_ * N_;
    k_logits<<<(BN + 3) / 4, 256, 0, stream>>>(V, W, ws_logits, BN);
    k_mask_scale<<<BN / ROWS_PER_BLK, 256, 0, stream>>>(V, ws_logits, tb, out_feat, out_mask);
}